// Round 22
// baseline (190.673 us; speedup 1.0000x reference)
//
#include <hip/hip_runtime.h>
#include <hip/hip_bf16.h>
#include <hip/hip_fp16.h>

#define UNITS 512
#define D_DEC 1024
#define D_ENC 1024
#define BATCH 32
#define S_LEN 2048

typedef _Float16 f16x8 __attribute__((ext_vector_type(8)));
typedef float f32x4 __attribute__((ext_vector_type(4)));

__device__ inline float tanh_fast(float x) {
    float e = __expf(2.f * x);
    return 1.f - 2.f * __builtin_amdgcn_rcpf(e + 1.f);
}

// ---------------- merged prep (r17, proven): W2 transpose+cvt + query
__global__ __launch_bounds__(256) void k_prep(const float* __restrict__ W2,
                                              _Float16* __restrict__ W2h,
                                              const float* __restrict__ dec,
                                              const float* __restrict__ W1,
                                              const float* __restrict__ b1,
                                              float* __restrict__ query) {
    const int tid = threadIdx.x;
    if (blockIdx.x < 512) {
        __shared__ float tile[32][33];
        const int kb = (blockIdx.x & 31) * 32;
        const int nb = (blockIdx.x >> 5) * 32;
        const int tx = tid & 31;
        const int ty = tid >> 5;
        for (int i = 0; i < 32; i += 8)
            tile[ty + i][tx] = W2[(size_t)(kb + ty + i) * UNITS + nb + tx];
        __syncthreads();
        for (int i = 0; i < 32; i += 8)
            W2h[(size_t)(nb + ty + i) * D_DEC + kb + tx] = (_Float16)tile[tx][ty + i];
    } else {
        const int qb = blockIdx.x - 512;
        const int u  = (qb >> 2) * 32 + (tid & 31);
        const int b  = (qb & 3) * 8 + (tid >> 5);
        float acc = b1[u];
        const float* dp = dec + (size_t)b * D_DEC;
        const float* wp = W1 + u;
        for (int d = 0; d < D_DEC; ++d) acc += dp[d] * wp[(size_t)d * UNITS];
        query[(size_t)b * UNITS + u] = acc;
    }
}

// ---------------- fused: r21 geometry (BM=128, N=512, BKK=64, 16 fat steps,
// 160 KiB arena, f16 trickle A + gload_lds B) + m201 phase discipline:
// each fat step = 2 phases {ds_read 8 frags ∥ staging issue -> s_barrier ->
// lgkmcnt(0)+sched_barrier -> setprio(1) -> 16 MFMA -> setprio(0) -> s_barrier}.
// vmcnt(0) only at step end (B has had a full-step flight; drain ~free).
#define BM 128
#define BKK 64
#define NSTEP (D_DEC / BKK)   // 16

__global__ __launch_bounds__(1024, 4) void k_fused(const float* __restrict__ enc,
                                                   const _Float16* __restrict__ W2h,
                                                   const float* __restrict__ query,
                                                   const float* __restrict__ b2,
                                                   const float* __restrict__ V,
                                                   float* __restrict__ scores,
                                                   float* __restrict__ chunk_m,
                                                   float* __restrict__ chunk_l,
                                                   float* __restrict__ part_ctx) {
    // arena: Ab[2] (2 x 16 KB f16 @ 0), Bb[2] (2 x 64 KB f16 @ 32768) = 160 KiB
    __shared__ __align__(16) char arena[163840];

    const int tid  = threadIdx.x;
    const int lane = tid & 63;
    const int w    = tid >> 6;     // 0..15
    const int wr   = w >> 3;       // 0..1
    const int wc   = w & 7;        // 0..7
    const int g    = lane >> 4;    // 0..3
    const int r    = lane & 15;    // 0..15
    const int blk  = blockIdx.x;   // 0..511
    const int row0 = blk * BM;
    const int bat  = row0 >> 11;

    int offA0[4], offA1[4], offB0[4], offB1[4];
#pragma unroll
    for (int q = 0; q < 4; ++q) {
        const int rowa = wr * 64 + q * 16 + r;
        const int s = (rowa & 7) << 4;
        offA0[q] = rowa * 128 + ((g * 16) ^ s);
        offA1[q] = rowa * 128 + ((64 + g * 16) ^ s);
    }
#pragma unroll
    for (int q = 0; q < 4; ++q) {
        const int rowb = wc * 64 + q * 16 + r;
        const int s = (rowb & 7) << 4;
        offB0[q] = rowb * 128 + ((g * 16) ^ s);
        offB1[q] = rowb * 128 + ((64 + g * 16) ^ s);
    }

    const int arow = tid >> 3;
    const int akc  = tid & 7;
    const float* asrc = enc + (size_t)(row0 + arow) * D_ENC + akc * 8;
    const int a_wbyte = arow * 128 + ((akc * 16) ^ ((arow & 7) << 4));

    const int browt = tid >> 3;
    const int bkb   = (tid & 7) * 16;
    const _Float16* bsrc0 = W2h + (size_t)browt * D_DEC
                            + ((bkb ^ ((browt & 7) << 4)) >> 1);
    const int bdst0 = tid * 16;

    f32x4 acc[4][4];
#pragma unroll
    for (int i = 0; i < 4; ++i)
#pragma unroll
        for (int j = 0; j < 4; ++j) acc[i][j] = (f32x4){0.f, 0.f, 0.f, 0.f};

    auto Abuf = [&](int b) -> char* { return arena + b * 16384; };
    auto Bbuf = [&](int b) -> char* { return arena + 32768 + b * 65536; };

    auto gldB = [&](int t, int buf) {
        char* base = Bbuf(buf);
#pragma unroll
        for (int i = 0; i < 4; ++i)
            __builtin_amdgcn_global_load_lds(
                (const __attribute__((address_space(1))) void*)
                    (bsrc0 + (size_t)i * 128 * D_DEC + t * BKK),
                (__attribute__((address_space(3))) void*)(base + bdst0 + i * 16384),
                16, 0, 0);
    };
    auto cvtA = [&](const float4& p0, const float4& p1, int buf) {
        f16x8 h = {(_Float16)p0.x, (_Float16)p0.y, (_Float16)p0.z, (_Float16)p0.w,
                   (_Float16)p1.x, (_Float16)p1.y, (_Float16)p1.z, (_Float16)p1.w};
        *reinterpret_cast<f16x8*>(Abuf(buf) + a_wbyte) = h;
    };

    // ---- prologue: A(0) values -> cvt; B(0) DMA; full drain.
    {
        float4 p0 = *reinterpret_cast<const float4*>(asrc);
        float4 p1 = *reinterpret_cast<const float4*>(asrc + 4);
        gldB(0, 0);
        cvtA(p0, p1, 0);
    }
    __syncthreads();

    // ---- main loop: 16 fat steps x 2 phases
    for (int t = 0; t < NSTEP; ++t) {
        const int cur = t & 1;
        const bool more = (t + 1 < NSTEP);
        const char* Ac = Abuf(cur);
        const char* Bc = Bbuf(cur);
        float4 p0, p1;

        // ---- phase 0: k-half 0; issue next-tile staging
        {
            f16x8 af[4], bf[4];
#pragma unroll
            for (int q = 0; q < 4; ++q) af[q] = *reinterpret_cast<const f16x8*>(Ac + offA0[q]);
#pragma unroll
            for (int q = 0; q < 4; ++q) bf[q] = *reinterpret_cast<const f16x8*>(Bc + offB0[q]);
            if (more) {
                p0 = *reinterpret_cast<const float4*>(asrc + (t + 1) * BKK);
                p1 = *reinterpret_cast<const float4*>(asrc + (t + 1) * BKK + 4);
                gldB(t + 1, cur ^ 1);
            }
            __builtin_amdgcn_s_barrier();
            asm volatile("s_waitcnt lgkmcnt(0)" ::: "memory");
            __builtin_amdgcn_sched_barrier(0);
            __builtin_amdgcn_s_setprio(1);
#pragma unroll
            for (int fr = 0; fr < 4; ++fr)
#pragma unroll
                for (int fc = 0; fc < 4; ++fc)
                    acc[fr][fc] = __builtin_amdgcn_mfma_f32_16x16x32_f16(
                        af[fr], bf[fc], acc[fr][fc], 0, 0, 0);
            __builtin_amdgcn_s_setprio(0);
            __builtin_amdgcn_s_barrier();
        }

        // ---- phase 1: k-half 1; write A(t+1); publish staging
        {
            f16x8 af[4], bf[4];
#pragma unroll
            for (int q = 0; q < 4; ++q) af[q] = *reinterpret_cast<const f16x8*>(Ac + offA1[q]);
#pragma unroll
            for (int q = 0; q < 4; ++q) bf[q] = *reinterpret_cast<const f16x8*>(Bc + offB1[q]);
            if (more) cvtA(p0, p1, cur ^ 1);
            __builtin_amdgcn_s_barrier();
            asm volatile("s_waitcnt lgkmcnt(0)" ::: "memory");
            __builtin_amdgcn_sched_barrier(0);
            __builtin_amdgcn_s_setprio(1);
#pragma unroll
            for (int fr = 0; fr < 4; ++fr)
#pragma unroll
                for (int fc = 0; fc < 4; ++fc)
                    acc[fr][fc] = __builtin_amdgcn_mfma_f32_16x16x32_f16(
                        af[fr], bf[fc], acc[fr][fc], 0, 0, 0);
            __builtin_amdgcn_s_setprio(0);
            asm volatile("s_waitcnt vmcnt(0)" ::: "memory");   // B(t+1) landed (full-step flight)
            __builtin_amdgcn_s_barrier();
        }
    }

    // ---- epilogue scratch reuses the arena (loop ended with a barrier)
    float* sc_part = (float*)arena;              // [8][BM] = 4 KB
    float* sc_e    = (float*)(arena + 4096);     // BM floats
    float* wred    = (float*)(arena + 4608);     // 4 floats

    // ---- epilogue 1: per-wave tanh*V partials over its 64-col group
    float qv[4], vv[4];
#pragma unroll
    for (int fc = 0; fc < 4; ++fc) {
        const int col = wc * 64 + fc * 16 + r;
        qv[fc] = query[(size_t)bat * UNITS + col] + b2[col];
        vv[fc] = V[col];
    }
    float ps[4][4];
#pragma unroll
    for (int fr = 0; fr < 4; ++fr)
#pragma unroll
        for (int i = 0; i < 4; ++i) ps[fr][i] = 0.f;
#pragma unroll
    for (int fc = 0; fc < 4; ++fc)
#pragma unroll
        for (int fr = 0; fr < 4; ++fr)
#pragma unroll
            for (int i = 0; i < 4; ++i)
                ps[fr][i] += tanh_fast(acc[fr][fc][i] + qv[fc]) * vv[fc];
#pragma unroll
    for (int off = 1; off < 16; off <<= 1)
#pragma unroll
        for (int fr = 0; fr < 4; ++fr)
#pragma unroll
            for (int i = 0; i < 4; ++i)
                ps[fr][i] += __shfl_xor(ps[fr][i], off, 64);
    if (r == 0)
#pragma unroll
        for (int fr = 0; fr < 4; ++fr)
#pragma unroll
            for (int i = 0; i < 4; ++i)
                sc_part[wc * BM + wr * 64 + fr * 16 + g * 4 + i] = ps[fr][i];
    __syncthreads();

    // ---- epilogue 2: chunk softmax stats over 128 rows (2 waves)
    float s_val = 0.f;
    if (tid < BM) {
#pragma unroll
        for (int ww = 0; ww < 8; ++ww) s_val += sc_part[ww * BM + tid];
        scores[(size_t)row0 + tid] = s_val;
        float m = s_val;
#pragma unroll
        for (int off = 32; off; off >>= 1) m = fmaxf(m, __shfl_xor(m, off, 64));
        if ((tid & 63) == 0) wred[tid >> 6] = m;
    }
    __syncthreads();
    if (tid < BM) {
        const float M = fmaxf(wred[0], wred[1]);
        const float e = __expf(s_val - M);
        sc_e[tid] = e;
        float l = e;
#pragma unroll
        for (int off = 32; off; off >>= 1) l += __shfl_xor(l, off, 64);
        if ((tid & 63) == 0) wred[2 + (tid >> 6)] = l;
    }
    __syncthreads();
    if (tid == 0) {
        chunk_m[blk] = fmaxf(wred[0], wred[1]);
        chunk_l[blk] = wred[2] + wred[3];
    }

    // ---- epilogue 3: partial context from this block's (cache-hot) enc tile
    {
        const int d = tid;
        float cx = 0.f;
        const float* ebase = enc + (size_t)row0 * D_ENC + d;
#pragma unroll 4
        for (int i = 0; i < BM; ++i)
            cx += sc_e[i] * ebase[(size_t)i * D_ENC];
        part_ctx[(size_t)blk * D_ENC + d] = cx;
    }
}

// ---------------- combine: per batch, merge 16 chunks (flash rescale)
__global__ __launch_bounds__(256) void k_combine(const float* __restrict__ scores,
                                                 const float* __restrict__ chunk_m,
                                                 const float* __restrict__ chunk_l,
                                                 const float* __restrict__ part_ctx,
                                                 float* __restrict__ out_ctx,
                                                 float* __restrict__ out_w) {
    const int b = blockIdx.x;
    const int tid = threadIdx.x;
    __shared__ float fc[16];
    __shared__ float Msh, Lsh;
    if (tid < 16) {
        const float m = chunk_m[b * 16 + tid];
        float M = m;
#pragma unroll
        for (int off = 8; off; off >>= 1) M = fmaxf(M, __shfl_xor(M, off, 16));
        const float f = __expf(m - M);
        float lf = chunk_l[b * 16 + tid] * f;
#pragma unroll
        for (int off = 8; off; off >>= 1) lf += __shfl_xor(lf, off, 16);
        fc[tid] = f;
        if (tid == 0) { Msh = M; Lsh = lf; }
    }
    __syncthreads();
    const float M = Msh;
    const float invL = 1.f / Lsh;
#pragma unroll
    for (int j = 0; j < 8; ++j) {
        const int s = tid + j * 256;
        out_w[(size_t)b * S_LEN + s] = __expf(scores[(size_t)b * S_LEN + s] - M) * invL;
    }
#pragma unroll
    for (int j = 0; j < 4; ++j) {
        const int d = tid + j * 256;
        float sacc = 0.f;
        for (int c = 0; c < 16; ++c)
            sacc += part_ctx[(size_t)(b * 16 + c) * D_ENC + d] * fc[c];
        out_ctx[(size_t)b * D_ENC + d] = sacc * invL;
    }
}

extern "C" void kernel_launch(void* const* d_in, const int* in_sizes, int n_in,
                              void* d_out, int out_size, void* d_ws, size_t ws_size,
                              hipStream_t stream) {
    const float* dec = (const float*)d_in[0];
    const float* enc = (const float*)d_in[1];
    const float* W1  = (const float*)d_in[2];
    const float* b1  = (const float*)d_in[3];
    const float* W2  = (const float*)d_in[4];
    const float* b2  = (const float*)d_in[5];
    const float* V   = (const float*)d_in[6];
    // bv unused: softmax shift-invariant

    float* out = (float*)d_out;
    float* out_ctx = out;                 // [32,1024]
    float* out_w   = out + BATCH * D_ENC; // [32,2048]

    char* ws = (char*)d_ws;
    _Float16* W2h  = (_Float16*)(ws);                          // 1 MB
    float* query   = (float*)(ws + (1 << 20));                 // 64 KB
    float* scores  = (float*)(ws + (1 << 20) + (1 << 16));     // 256 KB
    float* chunk_m = (float*)(ws + (1 << 20) + (1 << 16) + (1 << 18));          // 2 KB
    float* chunk_l = (float*)(ws + (1 << 20) + (1 << 16) + (1 << 18) + 4096);   // 2 KB
    float* part_ctx = (float*)(ws + (1 << 20) + (1 << 16) + (1 << 18) + 8192);  // 2 MB

    k_prep<<<576, 256, 0, stream>>>(W2, W2h, dec, W1, b1, query);
    k_fused<<<(BATCH * S_LEN) / BM, 1024, 0, stream>>>(enc, W2h, query, b2, V,
                                                       scores, chunk_m, chunk_l, part_ctx);
    k_combine<<<BATCH, 256, 0, stream>>>(scores, chunk_m, chunk_l, part_ctx,
                                         out_ctx, out_w);
}

// Round 23
// 160.929 us; speedup vs baseline: 1.1848x; 1.1848x over previous
//
#include <hip/hip_runtime.h>
#include <hip/hip_bf16.h>
#include <hip/hip_fp16.h>

#define UNITS 512
#define D_DEC 1024
#define D_ENC 1024
#define BATCH 32
#define S_LEN 2048

typedef _Float16 f16x8 __attribute__((ext_vector_type(8)));
typedef float f32x4 __attribute__((ext_vector_type(4)));

__device__ inline float tanh_fast(float x) {
    float e = __expf(2.f * x);
    return 1.f - 2.f * __builtin_amdgcn_rcpf(e + 1.f);
}

// ---------------- merged prep (r17, proven): W2 transpose+cvt + query
__global__ __launch_bounds__(256) void k_prep(const float* __restrict__ W2,
                                              _Float16* __restrict__ W2h,
                                              const float* __restrict__ dec,
                                              const float* __restrict__ W1,
                                              const float* __restrict__ b1,
                                              float* __restrict__ query) {
    const int tid = threadIdx.x;
    if (blockIdx.x < 512) {
        __shared__ float tile[32][33];
        const int kb = (blockIdx.x & 31) * 32;
        const int nb = (blockIdx.x >> 5) * 32;
        const int tx = tid & 31;
        const int ty = tid >> 5;
        for (int i = 0; i < 32; i += 8)
            tile[ty + i][tx] = W2[(size_t)(kb + ty + i) * UNITS + nb + tx];
        __syncthreads();
        for (int i = 0; i < 32; i += 8)
            W2h[(size_t)(nb + ty + i) * D_DEC + kb + tx] = (_Float16)tile[tx][ty + i];
    } else {
        const int qb = blockIdx.x - 512;
        const int u  = (qb >> 2) * 32 + (tid & 31);
        const int b  = (qb & 3) * 8 + (tid >> 5);
        float acc = b1[u];
        const float* dp = dec + (size_t)b * D_DEC;
        const float* wp = W1 + u;
        for (int d = 0; d < D_DEC; ++d) acc += dp[d] * wp[(size_t)d * UNITS];
        query[(size_t)b * UNITS + u] = acc;
    }
}

// ---------------- fused (r21, best measured: 161.0 us total): 128 rows x
// N=512, 1024 thr / 16 waves (2m x 8n), BKK=64 -> 16 fat steps.  A f16
// trickle staged (value loads early, cvt+write late), B f16 via
// global_load_lds with inverse-swizzled source, both double-buffered in a
// 160 KiB LDS arena.  One __syncthreads per step; prefetch distance 1
// (flight = one fat step).  All tiles 128 B rows, swizzle byte ^= (row&7)<<4.
// Session record: schedule-manipulation variants 0-for-7 (counted vmcnt x4,
// hoisting, phases+setprio, ILP restructure); wins were fusion (r8) and
// step-halving (r21).  All pipes <21% => latency-structure local minimum at
// this family's register/LDS budget.
#define BM 128
#define BKK 64
#define NSTEP (D_DEC / BKK)   // 16

__global__ __launch_bounds__(1024, 4) void k_fused(const float* __restrict__ enc,
                                                   const _Float16* __restrict__ W2h,
                                                   const float* __restrict__ query,
                                                   const float* __restrict__ b2,
                                                   const float* __restrict__ V,
                                                   float* __restrict__ scores,
                                                   float* __restrict__ chunk_m,
                                                   float* __restrict__ chunk_l,
                                                   float* __restrict__ part_ctx) {
    // arena: Ab[2] (2 x 16 KB f16 @ 0), Bb[2] (2 x 64 KB f16 @ 32768) = 160 KiB
    __shared__ __align__(16) char arena[163840];

    const int tid  = threadIdx.x;
    const int lane = tid & 63;
    const int w    = tid >> 6;     // 0..15
    const int wr   = w >> 3;       // 0..1
    const int wc   = w & 7;        // 0..7
    const int g    = lane >> 4;    // 0..3
    const int r    = lane & 15;    // 0..15
    const int blk  = blockIdx.x;   // 0..511
    const int row0 = blk * BM;
    const int bat  = row0 >> 11;

    // hoisted fragment byte offsets (rows are 128 B; swizzle (row&7)<<4)
    int offA0[4], offA1[4], offB0[4], offB1[4];
#pragma unroll
    for (int q = 0; q < 4; ++q) {
        const int rowa = wr * 64 + q * 16 + r;
        const int s = (rowa & 7) << 4;
        offA0[q] = rowa * 128 + ((g * 16) ^ s);
        offA1[q] = rowa * 128 + ((64 + g * 16) ^ s);
    }
#pragma unroll
    for (int q = 0; q < 4; ++q) {
        const int rowb = wc * 64 + q * 16 + r;
        const int s = (rowb & 7) << 4;
        offB0[q] = rowb * 128 + ((g * 16) ^ s);
        offB1[q] = rowb * 128 + ((64 + g * 16) ^ s);
    }

    // A trickle staging: row = tid>>3 (0..127), 8 f16 at k = (tid&7)*8
    const int arow = tid >> 3;
    const int akc  = tid & 7;
    const float* asrc = enc + (size_t)(row0 + arow) * D_ENC + akc * 8;
    const int a_wbyte = arow * 128 + ((akc * 16) ^ ((arow & 7) << 4));

    // B DMA staging: granule G = i*1024 + tid (i=0..3); row = i*128 + tid>>3
    const int browt = tid >> 3;
    const int bkb   = (tid & 7) * 16;
    const _Float16* bsrc0 = W2h + (size_t)browt * D_DEC
                            + ((bkb ^ ((browt & 7) << 4)) >> 1);
    const int bdst0 = tid * 16;

    f32x4 acc[4][4];
#pragma unroll
    for (int i = 0; i < 4; ++i)
#pragma unroll
        for (int j = 0; j < 4; ++j) acc[i][j] = (f32x4){0.f, 0.f, 0.f, 0.f};

    auto Abuf = [&](int b) -> char* { return arena + b * 16384; };
    auto Bbuf = [&](int b) -> char* { return arena + 32768 + b * 65536; };

    auto gldB = [&](int t, int buf) {
        char* base = Bbuf(buf);
#pragma unroll
        for (int i = 0; i < 4; ++i)
            __builtin_amdgcn_global_load_lds(
                (const __attribute__((address_space(1))) void*)
                    (bsrc0 + (size_t)i * 128 * D_DEC + t * BKK),
                (__attribute__((address_space(3))) void*)(base + bdst0 + i * 16384),
                16, 0, 0);
    };
    auto cvtA = [&](const float4& p0, const float4& p1, int buf) {
        f16x8 h = {(_Float16)p0.x, (_Float16)p0.y, (_Float16)p0.z, (_Float16)p0.w,
                   (_Float16)p1.x, (_Float16)p1.y, (_Float16)p1.z, (_Float16)p1.w};
        *reinterpret_cast<f16x8*>(Abuf(buf) + a_wbyte) = h;
    };
    auto compute = [&](int buf) {
        const char* Ac = Abuf(buf);
        const char* Bc = Bbuf(buf);
        {   // k-half 0
            f16x8 af[4], bf[4];
#pragma unroll
            for (int q = 0; q < 4; ++q) af[q] = *reinterpret_cast<const f16x8*>(Ac + offA0[q]);
#pragma unroll
            for (int q = 0; q < 4; ++q) bf[q] = *reinterpret_cast<const f16x8*>(Bc + offB0[q]);
#pragma unroll
            for (int fr = 0; fr < 4; ++fr)
#pragma unroll
                for (int fc = 0; fc < 4; ++fc)
                    acc[fr][fc] = __builtin_amdgcn_mfma_f32_16x16x32_f16(
                        af[fr], bf[fc], acc[fr][fc], 0, 0, 0);
        }
        {   // k-half 1
            f16x8 af[4], bf[4];
#pragma unroll
            for (int q = 0; q < 4; ++q) af[q] = *reinterpret_cast<const f16x8*>(Ac + offA1[q]);
#pragma unroll
            for (int q = 0; q < 4; ++q) bf[q] = *reinterpret_cast<const f16x8*>(Bc + offB1[q]);
#pragma unroll
            for (int fr = 0; fr < 4; ++fr)
#pragma unroll
                for (int fc = 0; fc < 4; ++fc)
                    acc[fr][fc] = __builtin_amdgcn_mfma_f32_16x16x32_f16(
                        af[fr], bf[fc], acc[fr][fc], 0, 0, 0);
        }
    };

    // ---- prologue: A(0) values -> cvt; B(0) DMA; full drain.
    {
        float4 p0 = *reinterpret_cast<const float4*>(asrc);
        float4 p1 = *reinterpret_cast<const float4*>(asrc + 4);
        gldB(0, 0);
        cvtA(p0, p1, 0);
    }
    __syncthreads();

    // ---- main loop: 16 steps, ONE barrier per step
    for (int t = 0; t < NSTEP; ++t) {
        const int cur = t & 1;
        float4 p0, p1;
        if (t + 1 < NSTEP) {
            p0 = *reinterpret_cast<const float4*>(asrc + (t + 1) * BKK);      // HBM first
            p1 = *reinterpret_cast<const float4*>(asrc + (t + 1) * BKK + 4);
            gldB(t + 1, cur ^ 1);                                             // L2 after
        }
        compute(cur);
        if (t + 1 < NSTEP) cvtA(p0, p1, cur ^ 1);
        __syncthreads();
    }

    // ---- epilogue scratch reuses the arena (loop ended with a barrier)
    float* sc_part = (float*)arena;              // [8][BM] = 4 KB
    float* sc_e    = (float*)(arena + 4096);     // BM floats
    float* wred    = (float*)(arena + 4608);     // 4 floats

    // ---- epilogue 1: per-wave tanh*V partials over its 64-col group
    float qv[4], vv[4];
#pragma unroll
    for (int fc = 0; fc < 4; ++fc) {
        const int col = wc * 64 + fc * 16 + r;
        qv[fc] = query[(size_t)bat * UNITS + col] + b2[col];
        vv[fc] = V[col];
    }
    float ps[4][4];
#pragma unroll
    for (int fr = 0; fr < 4; ++fr)
#pragma unroll
        for (int i = 0; i < 4; ++i) ps[fr][i] = 0.f;
#pragma unroll
    for (int fc = 0; fc < 4; ++fc)
#pragma unroll
        for (int fr = 0; fr < 4; ++fr)
#pragma unroll
            for (int i = 0; i < 4; ++i)
                ps[fr][i] += tanh_fast(acc[fr][fc][i] + qv[fc]) * vv[fc];
#pragma unroll
    for (int off = 1; off < 16; off <<= 1)
#pragma unroll
        for (int fr = 0; fr < 4; ++fr)
#pragma unroll
            for (int i = 0; i < 4; ++i)
                ps[fr][i] += __shfl_xor(ps[fr][i], off, 64);
    if (r == 0)
#pragma unroll
        for (int fr = 0; fr < 4; ++fr)
#pragma unroll
            for (int i = 0; i < 4; ++i)
                sc_part[wc * BM + wr * 64 + fr * 16 + g * 4 + i] = ps[fr][i];
    __syncthreads();

    // ---- epilogue 2: chunk softmax stats over 128 rows (2 waves)
    float s_val = 0.f;
    if (tid < BM) {
#pragma unroll
        for (int ww = 0; ww < 8; ++ww) s_val += sc_part[ww * BM + tid];
        scores[(size_t)row0 + tid] = s_val;
        float m = s_val;
#pragma unroll
        for (int off = 32; off; off >>= 1) m = fmaxf(m, __shfl_xor(m, off, 64));
        if ((tid & 63) == 0) wred[tid >> 6] = m;
    }
    __syncthreads();
    if (tid < BM) {
        const float M = fmaxf(wred[0], wred[1]);
        const float e = __expf(s_val - M);
        sc_e[tid] = e;
        float l = e;
#pragma unroll
        for (int off = 32; off; off >>= 1) l += __shfl_xor(l, off, 64);
        if ((tid & 63) == 0) wred[2 + (tid >> 6)] = l;
    }
    __syncthreads();
    if (tid == 0) {
        chunk_m[blk] = fmaxf(wred[0], wred[1]);
        chunk_l[blk] = wred[2] + wred[3];
    }

    // ---- epilogue 3: partial context from this block's (cache-hot) enc tile
    {
        const int d = tid;
        float cx = 0.f;
        const float* ebase = enc + (size_t)row0 * D_ENC + d;
#pragma unroll 4
        for (int i = 0; i < BM; ++i)
            cx += sc_e[i] * ebase[(size_t)i * D_ENC];
        part_ctx[(size_t)blk * D_ENC + d] = cx;
    }
}

// ---------------- combine: per batch, merge 16 chunks (flash rescale)
__global__ __launch_bounds__(256) void k_combine(const float* __restrict__ scores,
                                                 const float* __restrict__ chunk_m,
                                                 const float* __restrict__ chunk_l,
                                                 const float* __restrict__ part_ctx,
                                                 float* __restrict__ out_ctx,
                                                 float* __restrict__ out_w) {
    const int b = blockIdx.x;
    const int tid = threadIdx.x;
    __shared__ float fc[16];
    __shared__ float Msh, Lsh;
    if (tid < 16) {
        const float m = chunk_m[b * 16 + tid];
        float M = m;
#pragma unroll
        for (int off = 8; off; off >>= 1) M = fmaxf(M, __shfl_xor(M, off, 16));
        const float f = __expf(m - M);
        float lf = chunk_l[b * 16 + tid] * f;
#pragma unroll
        for (int off = 8; off; off >>= 1) lf += __shfl_xor(lf, off, 16);
        fc[tid] = f;
        if (tid == 0) { Msh = M; Lsh = lf; }
    }
    __syncthreads();
    const float M = Msh;
    const float invL = 1.f / Lsh;
#pragma unroll
    for (int j = 0; j < 8; ++j) {
        const int s = tid + j * 256;
        out_w[(size_t)b * S_LEN + s] = __expf(scores[(size_t)b * S_LEN + s] - M) * invL;
    }
#pragma unroll
    for (int j = 0; j < 4; ++j) {
        const int d = tid + j * 256;
        float sacc = 0.f;
        for (int c = 0; c < 16; ++c)
            sacc += part_ctx[(size_t)(b * 16 + c) * D_ENC + d] * fc[c];
        out_ctx[(size_t)b * D_ENC + d] = sacc * invL;
    }
}

extern "C" void kernel_launch(void* const* d_in, const int* in_sizes, int n_in,
                              void* d_out, int out_size, void* d_ws, size_t ws_size,
                              hipStream_t stream) {
    const float* dec = (const float*)d_in[0];
    const float* enc = (const float*)d_in[1];
    const float* W1  = (const float*)d_in[2];
    const float* b1  = (const float*)d_in[3];
    const float* W2  = (const float*)d_in[4];
    const float* b2  = (const float*)d_in[5];
    const float* V   = (const float*)d_in[6];
    // bv unused: softmax shift-invariant

    float* out = (float*)d_out;
    float* out_ctx = out;                 // [32,1024]
    float* out_w   = out + BATCH * D_ENC; // [32,2048]

    char* ws = (char*)d_ws;
    _Float16* W2h  = (_Float16*)(ws);                          // 1 MB
    float* query   = (float*)(ws + (1 << 20));                 // 64 KB
    float* scores  = (float*)(ws + (1 << 20) + (1 << 16));     // 256 KB
    float* chunk_m = (float*)(ws + (1 << 20) + (1 << 16) + (1 << 18));          // 2 KB
    float* chunk_l = (float*)(ws + (1 << 20) + (1 << 16) + (1 << 18) + 4096);   // 2 KB
    float* part_ctx = (float*)(ws + (1 << 20) + (1 << 16) + (1 << 18) + 8192);  // 2 MB

    k_prep<<<576, 256, 0, stream>>>(W2, W2h, dec, W1, b1, query);
    k_fused<<<(BATCH * S_LEN) / BM, 1024, 0, stream>>>(enc, W2h, query, b2, V,
                                                       scores, chunk_m, chunk_l, part_ctx);
    k_combine<<<BATCH, 256, 0, stream>>>(scores, chunk_m, chunk_l, part_ctx,
                                         out_ctx, out_w);
}